// Round 5
// baseline (223.591 us; speedup 1.0000x reference)
//
#include <hip/hip_runtime.h>
#include <math.h>

// Balanced 10-ary tree, depth 3: loss collapses to 4 block sums per row.
// s0 = x[t], s1 = sum of t's 10-block, s2 = sum of t's 100-block, s3 = row sum.
//
// History:
//  R1: fused final via __threadfence ticket = 4x regression — buffer_wbl2 +
//      buffer_inv PER BLOCK x 4096 flushed L2 under the streaming reads.
//  R2: TOK_PER_WAVE 4 = +6 us (VGPR liveness). R3: single-pass s1/s2 = neutral.
//  R4: 4096 persistent waves x 8 rows = +13 us (problem is TLP-fed: fewer
//      waves = less outstanding traffic; 16384 short waves beat deep pipelines).
//  => hll_main body below is byte-identical to the 203.85 us round-0 best.
//  R5: fuse the final reduce WITHOUT any cache-maintenance: partial stores are
//      agent-scope sc1 write-through (bypass the non-coherent per-XCD L2, land
//      at the coherent L3), ordered before a RELAXED agent ticket atomicAdd by
//      a bare s_waitcnt vmcnt(0). No buffer_wbl2/buffer_inv anywhere. The
//      last-finishing block reads partials with agent-scope loads (sc1, bypass
//      its own L2) and reduces in hll_final's exact arithmetic order.
#define N_TOKENS     32768
#define NUM_CLASSES  1000
#define IGNORE_INDEX (-100)
#define WAVES_PER_BLK 4
#define TOK_PER_WAVE 2
#define NBLOCKS      (N_TOKENS / (WAVES_PER_BLK * TOK_PER_WAVE))  // 4096

// Monotone ticket in module .data (NOT the poisoned workspace). Each full
// dispatch adds exactly NBLOCKS (power of two), so ((old+1) & (NBLOCKS-1))==0
// marks the last block of every iteration across graph replays; wraparound at
// 2^32 is harmless.
__device__ unsigned g_ticket = 0u;

union F2U { float2 f; unsigned long long u; };

__global__ __launch_bounds__(256) void hll_fused(
    const float* __restrict__ inputs,    // [N_TOKENS, NUM_CLASSES]
    const int*   __restrict__ target,    // [N_TOKENS]
    const float* __restrict__ weights,   // [NUM_CLASSES, 3]
    float2* __restrict__ partials,       // [NBLOCKS] {loss_sum, cnt} in ws
    float*  __restrict__ out)            // [1]
{
    const int wave = threadIdx.x >> 6;
    const int lane = threadIdx.x & 63;
    const int n0 = (blockIdx.x * WAVES_PER_BLK + wave) * TOK_PER_WAVE;
    const int n1 = n0 + 1;

    const float* __restrict__ rowpA = inputs + (size_t)n0 * NUM_CLASSES;
    const float* __restrict__ rowpB = inputs + (size_t)n1 * NUM_CLASSES;
    const float4* __restrict__ rowA = (const float4*)rowpA;
    const float4* __restrict__ rowB = (const float4*)rowpB;

    // ---- issue all streaming loads up-front (8 independent 1 KB wave-loads)
    const float4 a0 = rowA[lane];
    const float4 a1 = rowA[lane + 64];
    const float4 a2 = rowA[lane + 128];
    float4 a3 = make_float4(0.f, 0.f, 0.f, 0.f);
    if (lane < 58) a3 = rowA[lane + 192];          // 250 float4s per row
    const float4 b0 = rowB[lane];
    const float4 b1 = rowB[lane + 64];
    const float4 b2 = rowB[lane + 128];
    float4 b3 = make_float4(0.f, 0.f, 0.f, 0.f);
    if (lane < 58) b3 = rowB[lane + 192];

    const int tA = target[n0];
    const int tB = target[n1];
    const bool validA = (tA != IGNORE_INDEX);
    const bool validB = (tB != IGNORE_INDEX);
    const int ttA = validA ? tA : 0;
    const int ttB = validB ? tB : 0;

    // ---- pass-2 gathers: rows are hot in this CU's L1 (empirically best)
    float4 vs2A = make_float4(0.f, 0.f, 0.f, 0.f);
    float4 vs2B = make_float4(0.f, 0.f, 0.f, 0.f);
    if (lane < 25) {
        vs2A = rowA[(ttA / 100) * 25 + lane];      // 100-block = 25 float4s
        vs2B = rowB[(ttB / 100) * 25 + lane];
    }
    float s1A = (lane < 10) ? rowpA[(ttA / 10) * 10 + lane] : 0.f;
    float s1B = (lane < 10) ? rowpB[(ttB / 10) * 10 + lane] : 0.f;
    const float s0A = rowpA[ttA];
    const float s0B = rowpB[ttB];

    float s3A = ((a0.x + a0.y) + (a0.z + a0.w)) + ((a1.x + a1.y) + (a1.z + a1.w))
              + ((a2.x + a2.y) + (a2.z + a2.w)) + ((a3.x + a3.y) + (a3.z + a3.w));
    float s3B = ((b0.x + b0.y) + (b0.z + b0.w)) + ((b1.x + b1.y) + (b1.z + b1.w))
              + ((b2.x + b2.y) + (b2.z + b2.w)) + ((b3.x + b3.y) + (b3.z + b3.w));
    float s2A = (vs2A.x + vs2A.y) + (vs2A.z + vs2A.w);
    float s2B = (vs2B.x + vs2B.y) + (vs2B.z + vs2B.w);

    // ---- 6 independent shuffle chains, interleaved by the scheduler
    #pragma unroll
    for (int off = 32; off >= 1; off >>= 1) {
        s3A += __shfl_down(s3A, off, 64);
        s3B += __shfl_down(s3B, off, 64);
        s2A += __shfl_down(s2A, off, 64);
        s2B += __shfl_down(s2B, off, 64);
        s1A += __shfl_down(s1A, off, 64);
        s1B += __shfl_down(s1B, off, 64);
    }

    __shared__ float rl[WAVES_PER_BLK], rc[WAVES_PER_BLK];
    if (lane == 0) {
        float loss = 0.f, cnt = 0.f;
        if (validA) {
            const float w0 = weights[ttA * 3 + 0];
            const float w1 = weights[ttA * 3 + 1];
            const float w2 = weights[ttA * 3 + 2];
            // reference: num = where(num!=0, -log(num/den), num); 0 -> 0
            const float l0 = (s0A != 0.f) ? -logf(s0A / s1A) : 0.f;
            const float l1 = (s1A != 0.f) ? -logf(s1A / s2A) : 0.f;
            const float l2 = (s2A != 0.f) ? -logf(s2A / s3A) : 0.f;
            loss += w0 * l0 + w1 * l1 + w2 * l2;
            cnt += 1.f;
        }
        if (validB) {
            const float w0 = weights[ttB * 3 + 0];
            const float w1 = weights[ttB * 3 + 1];
            const float w2 = weights[ttB * 3 + 2];
            const float l0 = (s0B != 0.f) ? -logf(s0B / s1B) : 0.f;
            const float l1 = (s1B != 0.f) ? -logf(s1B / s2B) : 0.f;
            const float l2 = (s2B != 0.f) ? -logf(s2B / s3B) : 0.f;
            loss += w0 * l0 + w1 * l1 + w2 * l2;
            cnt += 1.f;
        }
        rl[wave] = loss;
        rc[wave] = cnt;
    }
    __syncthreads();

    // ---- publish partial (agent-scope, write-through sc1 -> coherent L3),
    //      then take a RELAXED ticket. No L2 writeback/invalidate anywhere.
    __shared__ bool is_last;
    if (threadIdx.x == 0) {
        F2U z;
        z.f = make_float2((rl[0] + rl[1]) + (rl[2] + rl[3]),
                          (rc[0] + rc[1]) + (rc[2] + rc[3]));
        __hip_atomic_store((unsigned long long*)(partials + blockIdx.x), z.u,
                           __ATOMIC_RELAXED, __HIP_MEMORY_SCOPE_AGENT);
        // order: partial must be at the coherence point before the ticket.
        asm volatile("s_waitcnt vmcnt(0)" ::: "memory");
        const unsigned old = __hip_atomic_fetch_add(&g_ticket, 1u,
                           __ATOMIC_RELAXED, __HIP_MEMORY_SCOPE_AGENT);
        is_last = (((old + 1u) & (NBLOCKS - 1u)) == 0u);
    }
    __syncthreads();
    if (!is_last) return;

    // ---- last block: reduce 4096 float2 (32 KB) in hll_final's exact order.
    //      Agent-scope loads (sc1) bypass this XCD's (possibly stale) L2.
    const unsigned long long* __restrict__ pu = (const unsigned long long*)partials;
    float s = 0.f, c = 0.f;
    for (int i = threadIdx.x; i < NBLOCKS / 2; i += 256) {
        F2U lo, hi;   // {v.x,v.y} and {v.z,v.w} of hll_final's float4
        lo.u = __hip_atomic_load(pu + 2 * i,     __ATOMIC_RELAXED, __HIP_MEMORY_SCOPE_AGENT);
        hi.u = __hip_atomic_load(pu + 2 * i + 1, __ATOMIC_RELAXED, __HIP_MEMORY_SCOPE_AGENT);
        s += lo.f.x + hi.f.x;                      // == v.x + v.z
        c += lo.f.y + hi.f.y;                      // == v.y + v.w
    }
    #pragma unroll
    for (int off = 32; off >= 1; off >>= 1) {
        s += __shfl_down(s, off, 64);
        c += __shfl_down(c, off, 64);
    }
    __shared__ float ss[WAVES_PER_BLK], sc[WAVES_PER_BLK];
    if (lane == 0) { ss[wave] = s; sc[wave] = c; }
    __syncthreads();
    if (threadIdx.x == 0) {
        const float S  = (ss[0] + ss[1]) + (ss[2] + ss[3]);
        const float Ct = (sc[0] + sc[1]) + (sc[2] + sc[3]);
        out[0] = S / fmaxf(Ct, 1.0f);              // visible via kernel-end release
    }
}

extern "C" void kernel_launch(void* const* d_in, const int* in_sizes, int n_in,
                              void* d_out, int out_size, void* d_ws, size_t ws_size,
                              hipStream_t stream) {
    const float* inputs  = (const float*)d_in[0];   // [32768, 1000] f32
    const int*   target  = (const int*)d_in[1];     // [32768] int
    // d_in[2] = onehot_num, d_in[3] = onehot_den — structurally implied, unused
    const float* weights = (const float*)d_in[4];   // [1000, 3] f32
    float* out = (float*)d_out;

    float2* partials = (float2*)d_ws;               // 4096 float2 = 32 KB

    hll_fused<<<NBLOCKS, 256, 0, stream>>>(inputs, target, weights, partials, out);
}

// Round 6
// 204.885 us; speedup vs baseline: 1.0913x; 1.0913x over previous
//
#include <hip/hip_runtime.h>
#include <math.h>

// Balanced 10-ary tree, depth 3: loss collapses to 4 block sums per row.
// s0 = x[t], s1 = sum of t's 10-block, s2 = sum of t's 100-block, s3 = row sum.
//
// FINAL: byte-exact revert to the round-0 / previous-session optimum
// (measured 203.85 us, absmax 0.0). Session scoreboard of perturbations:
//  R1 fused threadfence ticket  +146 us (per-block L2 wb/inv storm)
//  R2 4 tokens/wave             +6 us  (VGPR liveness; loads get sunk)
//  R3 single-pass pred. s1/s2   +3 us  (gather pass was not the limiter)
//  R4 persistent waves+pipeline +13 us (TLP-fed problem; fewer waves = less
//                                       outstanding traffic)
//  R5 fused agent-scope sc1     +20 us (single-line ticket serializes tails)
// The timed window is dominated by the harness reset train (~150 us of
// 500 MiB fills at 85-87% HBM peak — at roofline); the kernel residual
// (~54 us) resisted five orthogonal structural attacks.
#define N_TOKENS     32768
#define NUM_CLASSES  1000
#define IGNORE_INDEX (-100)
#define WAVES_PER_BLK 4
#define TOK_PER_WAVE 2
#define NBLOCKS      (N_TOKENS / (WAVES_PER_BLK * TOK_PER_WAVE))  // 4096

// Kernel 1: each wave owns 2 tokens. All 8 streaming float4 loads (2 rows x
// 4 KB) are issued before any use — 8 KB in flight per wave. Subtree sums via
// L1-hot second-pass gathers, shuffle reductions, one float2 partial per block.
__global__ __launch_bounds__(256) void hll_main(
    const float* __restrict__ inputs,    // [N_TOKENS, NUM_CLASSES]
    const int*   __restrict__ target,    // [N_TOKENS]
    const float* __restrict__ weights,   // [NUM_CLASSES, 3]
    float2* __restrict__ partials)       // [NBLOCKS] {loss_sum, cnt}
{
    const int wave = threadIdx.x >> 6;
    const int lane = threadIdx.x & 63;
    const int n0 = (blockIdx.x * WAVES_PER_BLK + wave) * TOK_PER_WAVE;
    const int n1 = n0 + 1;

    const float* __restrict__ rowpA = inputs + (size_t)n0 * NUM_CLASSES;
    const float* __restrict__ rowpB = inputs + (size_t)n1 * NUM_CLASSES;
    const float4* __restrict__ rowA = (const float4*)rowpA;
    const float4* __restrict__ rowB = (const float4*)rowpB;

    // ---- issue all streaming loads up-front (8 independent 1 KB wave-loads)
    const float4 a0 = rowA[lane];
    const float4 a1 = rowA[lane + 64];
    const float4 a2 = rowA[lane + 128];
    float4 a3 = make_float4(0.f, 0.f, 0.f, 0.f);
    if (lane < 58) a3 = rowA[lane + 192];          // 250 float4s per row
    const float4 b0 = rowB[lane];
    const float4 b1 = rowB[lane + 64];
    const float4 b2 = rowB[lane + 128];
    float4 b3 = make_float4(0.f, 0.f, 0.f, 0.f);
    if (lane < 58) b3 = rowB[lane + 192];

    const int tA = target[n0];
    const int tB = target[n1];
    const bool validA = (tA != IGNORE_INDEX);
    const bool validB = (tB != IGNORE_INDEX);
    const int ttA = validA ? tA : 0;
    const int ttB = validB ? tB : 0;

    // ---- pass-2 gathers: rows are hot in this CU's L1 (4 KB row vs 32 KB L1)
    float4 vs2A = make_float4(0.f, 0.f, 0.f, 0.f);
    float4 vs2B = make_float4(0.f, 0.f, 0.f, 0.f);
    if (lane < 25) {
        vs2A = rowA[(ttA / 100) * 25 + lane];      // 100-block = 25 float4s
        vs2B = rowB[(ttB / 100) * 25 + lane];
    }
    float s1A = (lane < 10) ? rowpA[(ttA / 10) * 10 + lane] : 0.f;
    float s1B = (lane < 10) ? rowpB[(ttB / 10) * 10 + lane] : 0.f;
    const float s0A = rowpA[ttA];
    const float s0B = rowpB[ttB];

    float s3A = ((a0.x + a0.y) + (a0.z + a0.w)) + ((a1.x + a1.y) + (a1.z + a1.w))
              + ((a2.x + a2.y) + (a2.z + a2.w)) + ((a3.x + a3.y) + (a3.z + a3.w));
    float s3B = ((b0.x + b0.y) + (b0.z + b0.w)) + ((b1.x + b1.y) + (b1.z + b1.w))
              + ((b2.x + b2.y) + (b2.z + b2.w)) + ((b3.x + b3.y) + (b3.z + b3.w));
    float s2A = (vs2A.x + vs2A.y) + (vs2A.z + vs2A.w);
    float s2B = (vs2B.x + vs2B.y) + (vs2B.z + vs2B.w);

    // ---- 6 independent shuffle chains, interleaved by the scheduler
    #pragma unroll
    for (int off = 32; off >= 1; off >>= 1) {
        s3A += __shfl_down(s3A, off, 64);
        s3B += __shfl_down(s3B, off, 64);
        s2A += __shfl_down(s2A, off, 64);
        s2B += __shfl_down(s2B, off, 64);
        s1A += __shfl_down(s1A, off, 64);
        s1B += __shfl_down(s1B, off, 64);
    }

    __shared__ float rl[WAVES_PER_BLK], rc[WAVES_PER_BLK];
    if (lane == 0) {
        float loss = 0.f, cnt = 0.f;
        if (validA) {
            const float w0 = weights[ttA * 3 + 0];
            const float w1 = weights[ttA * 3 + 1];
            const float w2 = weights[ttA * 3 + 2];
            // reference: num = where(num!=0, -log(num/den), num); 0 -> 0
            const float l0 = (s0A != 0.f) ? -logf(s0A / s1A) : 0.f;
            const float l1 = (s1A != 0.f) ? -logf(s1A / s2A) : 0.f;
            const float l2 = (s2A != 0.f) ? -logf(s2A / s3A) : 0.f;
            loss += w0 * l0 + w1 * l1 + w2 * l2;
            cnt += 1.f;
        }
        if (validB) {
            const float w0 = weights[ttB * 3 + 0];
            const float w1 = weights[ttB * 3 + 1];
            const float w2 = weights[ttB * 3 + 2];
            const float l0 = (s0B != 0.f) ? -logf(s0B / s1B) : 0.f;
            const float l1 = (s1B != 0.f) ? -logf(s1B / s2B) : 0.f;
            const float l2 = (s2B != 0.f) ? -logf(s2B / s3B) : 0.f;
            loss += w0 * l0 + w1 * l1 + w2 * l2;
            cnt += 1.f;
        }
        rl[wave] = loss;
        rc[wave] = cnt;
    }
    __syncthreads();
    if (threadIdx.x == 0) {
        partials[blockIdx.x] = make_float2((rl[0] + rl[1]) + (rl[2] + rl[3]),
                                           (rc[0] + rc[1]) + (rc[2] + rc[3]));
    }
}

// Kernel 2: reduce NBLOCKS float2 (32 KB, L2-hot) -> scalar mean.
__global__ __launch_bounds__(256) void hll_final(
    const float4* __restrict__ p4,      // [NBLOCKS/2] {s,c,s,c}
    float* __restrict__ out)
{
    const int wave = threadIdx.x >> 6;
    const int lane = threadIdx.x & 63;
    float s = 0.f, c = 0.f;
    for (int i = threadIdx.x; i < NBLOCKS / 2; i += 256) {
        const float4 v = p4[i];
        s += v.x + v.z;
        c += v.y + v.w;
    }
    #pragma unroll
    for (int off = 32; off >= 1; off >>= 1) {
        s += __shfl_down(s, off, 64);
        c += __shfl_down(c, off, 64);
    }
    __shared__ float ss[4], sc[4];
    if (lane == 0) { ss[wave] = s; sc[wave] = c; }
    __syncthreads();
    if (threadIdx.x == 0) {
        const float S  = (ss[0] + ss[1]) + (ss[2] + ss[3]);
        const float Ct = (sc[0] + sc[1]) + (sc[2] + sc[3]);
        out[0] = S / fmaxf(Ct, 1.0f);
    }
}

extern "C" void kernel_launch(void* const* d_in, const int* in_sizes, int n_in,
                              void* d_out, int out_size, void* d_ws, size_t ws_size,
                              hipStream_t stream) {
    const float* inputs  = (const float*)d_in[0];   // [32768, 1000] f32
    const int*   target  = (const int*)d_in[1];     // [32768] int
    // d_in[2] = onehot_num, d_in[3] = onehot_den — structurally implied, unused
    const float* weights = (const float*)d_in[4];   // [1000, 3] f32
    float* out = (float*)d_out;

    float2* partials = (float2*)d_ws;               // 4096 float2 = 32 KB

    hll_main<<<NBLOCKS, 256, 0, stream>>>(inputs, target, weights, partials);
    hll_final<<<1, 256, 0, stream>>>((const float4*)partials, out);
}